// Round 12
// baseline (240.747 us; speedup 1.0000x reference)
//
#include <hip/hip_runtime.h>
#include <stdint.h>
#include <stddef.h>

#define Bsz 16384
#define Hsz 512
#define KG 1536   // K of gemm2 == row stride of A
#define KA 1024   // K of gemm1
#define NT2 24    // gemm2 K tiles of 64

typedef float f32x4 __attribute__((ext_vector_type(4)));
typedef short bf16x8 __attribute__((ext_vector_type(8)));
typedef unsigned short u16;
typedef unsigned int u32;

__device__ __forceinline__ u16 f2bf(float f) {
  union { float f; unsigned u; } v; v.f = f;
  return (u16)((v.u + 0x7fffu + ((v.u >> 16) & 1u)) >> 16);
}
__device__ __forceinline__ float bf2f(u16 h) {
  union { unsigned u; float f; } v; v.u = ((unsigned)h) << 16;
  return v.f;
}
__device__ __forceinline__ float sigm(float x) {
  return 1.0f / (1.0f + __expf(-x));
}
__device__ __forceinline__ float tanh_(float x) {
  x = fminf(fmaxf(x, -15.0f), 15.0f);
  float e = __expf(2.0f * x);
  return (e - 1.0f) / (e + 1.0f);
}

__device__ __forceinline__ void gload_lds16(const u16* g, u16* l) {
  __builtin_amdgcn_global_load_lds(
      (__attribute__((address_space(1))) void*)(g),
      (__attribute__((address_space(3))) void*)(l), 16, 0, 0);
}

#define VMCNT(n) asm volatile("s_waitcnt vmcnt(" #n ")" ::: "memory")
#define LGKM0() { asm volatile("s_waitcnt lgkmcnt(0)" ::: "memory"); \
                  __builtin_amdgcn_sched_barrier(0); }
#define BAR() { asm volatile("" ::: "memory"); __builtin_amdgcn_s_barrier(); \
                asm volatile("" ::: "memory"); }
#define DSR(dst, addr, OFF) \
  asm volatile("ds_read_b128 %0, %1 offset:" #OFF : "=v"(dst) : "v"(addr));

// ---- cast h_prev | x_t into bf16 A[B][1536] (cols 0..1023) ----
__global__ __launch_bounds__(256) void prep_A_kernel(
    const float* __restrict__ h_prev, const float* __restrict__ x_t,
    u16* __restrict__ A) {
  const int b = blockIdx.x;
  const int q = threadIdx.x;
  const int qq = q & 127;
  const float4* src = (q < 128) ? (const float4*)h_prev : (const float4*)x_t;
  float4 v = src[(size_t)b * 128 + qq];
  ushort4 o;
  o.x = f2bf(v.x); o.y = f2bf(v.y); o.z = f2bf(v.z); o.w = f2bf(v.w);
  *(ushort4*)(A + (size_t)b * KG + (size_t)q * 4) = o;
}

// ---- transpose-cast: in[R][C] fp32 -> out[C][R] bf16 ----
__global__ __launch_bounds__(256) void transpose_cast_kernel(
    const float* __restrict__ in, u16* __restrict__ out, int R, int C) {
  __shared__ float tile[32][33];
  const int c0 = blockIdx.x * 32;
  const int r0 = blockIdx.y * 32;
  const int tx = threadIdx.x;
  const int ty = threadIdx.y;
  #pragma unroll
  for (int i = ty; i < 32; i += 8)
    tile[i][tx] = in[(size_t)(r0 + i) * C + (c0 + tx)];
  __syncthreads();
  #pragma unroll
  for (int i = ty; i < 32; i += 8)
    out[(size_t)(c0 + i) * R + (r0 + tx)] = f2bf(tile[tx][i]);
}

// ---- GEMM1: s = tanh(A[:,0:1024] @ Wst^T + delta*ws_last + bs) -> A[:,1024:1536]
__global__ __launch_bounds__(256, 2) void gemm1_kernel(
    const u16* __restrict__ A, const u16* __restrict__ Wst,
    const float* __restrict__ Ws, const float* __restrict__ bs,
    const float* __restrict__ delta, u16* __restrict__ Aout) {
  __shared__ __attribute__((aligned(16))) u16 Als[128][32];
  __shared__ __attribute__((aligned(16))) u16 Bls[128][32];
  const int t = threadIdx.x;
  const int w = t >> 6, l = t & 63;
  const int bm0 = blockIdx.y * 128;
  const int bn0 = blockIdx.x * 128;
  const int wm = w >> 1, wn = w & 1;

  f32x4 zv = {0.f, 0.f, 0.f, 0.f};
  f32x4 acc[4][4];
  #pragma unroll
  for (int i = 0; i < 4; ++i)
    #pragma unroll
    for (int j = 0; j < 4; ++j) acc[i][j] = zv;

  const int r = t >> 2, q = t & 3;
  const u16* gA0 = A + (size_t)(bm0 + r) * KG + q * 8;
  const u16* gA1 = A + (size_t)(bm0 + 64 + r) * KG + q * 8;
  const u16* gB0 = Wst + (size_t)(bn0 + r) * KA + q * 8;
  const u16* gB1 = Wst + (size_t)(bn0 + 64 + r) * KA + q * 8;
  u16* lA0 = &Als[0][0] + w * 512;
  u16* lA1 = &Als[0][0] + 2048 + w * 512;
  u16* lB0 = &Bls[0][0] + w * 512;
  u16* lB1 = &Bls[0][0] + 2048 + w * 512;

  const int frow = l & 15;
  const int kofs = (l >> 4) * 8;

  for (int kt = 0; kt < KA / 32; ++kt) {
    const int ko = kt * 32;
    gload_lds16(gA0 + ko, lA0);
    gload_lds16(gA1 + ko, lA1);
    gload_lds16(gB0 + ko, lB0);
    gload_lds16(gB1 + ko, lB1);
    __syncthreads();
    bf16x8 af[4], bfv[4];
    #pragma unroll
    for (int mi = 0; mi < 4; ++mi)
      af[mi] = *(const bf16x8*)&Als[wm * 64 + mi * 16 + frow][kofs];
    #pragma unroll
    for (int ni = 0; ni < 4; ++ni)
      bfv[ni] = *(const bf16x8*)&Bls[wn * 64 + ni * 16 + frow][kofs];
    #pragma unroll
    for (int mi = 0; mi < 4; ++mi)
      #pragma unroll
      for (int ni = 0; ni < 4; ++ni)
        acc[mi][ni] = __builtin_amdgcn_mfma_f32_16x16x32_bf16(
            af[mi], bfv[ni], acc[mi][ni], 0, 0, 0);
    __syncthreads();
  }

  #pragma unroll
  for (int ni = 0; ni < 4; ++ni) {
    const int col = bn0 + wn * 64 + ni * 16 + (l & 15);
    const float wsl = Ws[(size_t)1024 * 512 + col];
    const float bsv = bs[col];
    #pragma unroll
    for (int mi = 0; mi < 4; ++mi) {
      #pragma unroll
      for (int rr = 0; rr < 4; ++rr) {
        const int row = bm0 + wm * 64 + mi * 16 + (l >> 4) * 4 + rr;
        const float z = acc[mi][ni][rr] + delta[row] * wsl + bsv;
        Aout[(size_t)row * KG + 1024 + col] = f2bf(tanh_(z));
      }
    }
  }
}

// ---- GEMM2, literal m201 geometry (unfused): z = A[16384,1536] @ Wgt^T ----
// 256x256 tile, BK=64, 512 thr (8 waves 2Mx4N), per-wave C 128x64,
// acc[8][4] f32x4 = 128. LDS 128KB: LA/LB[2 buf][2 half][128x64].
// Tile t lives in buf t&1. Group j (4 phases) consumes tile j, stages
// tile j+1 (1 half-tile per phase); group-end vmcnt(0)+bar (stages led
// by ~4 phases). Phase: reads -> stage -> bar -> lgkm0 -> setprio 16 MFMA
// -> bar. Gray walk (qm,qn): 00 -> 01 -> 11 -> 10 (reads 12/4/8/4).
// Swizzle: 128B rows, 16B chunk c stored from global chunk c^(row&7)
// (linear DMA dest, pre-swizzled src); read chunk (ks*4+kq)^(frow&7).
__global__ __launch_bounds__(512, 2) void gemm2_t(
    const u16* __restrict__ A, const u16* __restrict__ Wgt,
    u16* __restrict__ z) {
  __shared__ __attribute__((aligned(16))) u16 LA[2][2][8192];
  __shared__ __attribute__((aligned(16))) u16 LB[2][2][8192];
  const int t5 = threadIdx.x;
  const int w = t5 >> 6, l = t5 & 63;
  const int bid = blockIdx.x;                 // 640 = 64 rb x 10 cb
  const int swz = (bid & 7) * 80 + (bid >> 3);
  const int rb = swz / 10, cb = swz - rb * 10;
  const int am0 = rb * 256;
  const int bn0 = cb * 256;
  const int wm = w >> 2, wn = w & 3;

  const u16 *As00, *As01, *As10, *As11, *Bs00, *Bs01, *Bs10, *Bs11;
#define MKSRC(P, MAT, BASE, H, J) { \
    u32 d = (u32)(t5 + (J) * 512) * 16; \
    u32 row = d >> 7; u32 ch = ((d >> 4) & 7) ^ (row & 7); \
    P = MAT + (size_t)((BASE) + (H) * 128 + row) * KG + ch * 8; }
  MKSRC(As00, A, am0, 0, 0) MKSRC(As01, A, am0, 0, 1)
  MKSRC(As10, A, am0, 1, 0) MKSRC(As11, A, am0, 1, 1)
  MKSRC(Bs00, Wgt, bn0, 0, 0) MKSRC(Bs01, Wgt, bn0, 0, 1)
  MKSRC(Bs10, Wgt, bn0, 1, 0) MKSRC(Bs11, Wgt, bn0, 1, 1)
#undef MKSRC

  const int frow = l & 15, kq = l >> 4;
  const int f3 = frow & 3, fb2 = (frow >> 2) & 1;
  const u32 laneC = (u32)((kq ^ f3) * 16);
  const u32 ldsA0b = (u32)(uintptr_t)&LA[0][0][0];
  const u32 ldsB0b = (u32)(uintptr_t)&LB[0][0][0];
  // addr regs per kstep (ks XOR fb2 folded in); buf/qm/qn/fi/ni in literal
  const u32 aAddr0 = ldsA0b + (u32)wm * 16384 + (u32)frow * 128 + (u32)((0 ^ fb2) * 64) + laneC;
  const u32 aAddr1 = ldsA0b + (u32)wm * 16384 + (u32)frow * 128 + (u32)((1 ^ fb2) * 64) + laneC;
  const u32 bAddr0 = ldsB0b + (u32)(wn >> 1) * 16384 + (u32)(wn & 1) * 8192 +
                     (u32)frow * 128 + (u32)((0 ^ fb2) * 64) + laneC;
  const u32 bAddr1 = ldsB0b + (u32)(wn >> 1) * 16384 + (u32)(wn & 1) * 8192 +
                     (u32)frow * 128 + (u32)((1 ^ fb2) * 64) + laneC;

  bf16x8 af00, af01, af10, af11, af20, af21, af30, af31;
  bf16x8 bf00, bf01, bf10, bf11;
  f32x4 acc[8][4];
  f32x4 zv = {0.f, 0.f, 0.f, 0.f};
  #pragma unroll
  for (int mi = 0; mi < 8; ++mi)
    #pragma unroll
    for (int ni = 0; ni < 4; ++ni) acc[mi][ni] = zv;

  // A-frag reads: af(fi,ks); offsets buf*32768 + qm*8192 + fi*2048
#define RD_A_B0Q0 { DSR(af00, aAddr0, 0) DSR(af01, aAddr1, 0) \
    DSR(af10, aAddr0, 2048) DSR(af11, aAddr1, 2048) \
    DSR(af20, aAddr0, 4096) DSR(af21, aAddr1, 4096) \
    DSR(af30, aAddr0, 6144) DSR(af31, aAddr1, 6144) }
#define RD_A_B0Q1 { DSR(af00, aAddr0, 8192) DSR(af01, aAddr1, 8192) \
    DSR(af10, aAddr0, 10240) DSR(af11, aAddr1, 10240) \
    DSR(af20, aAddr0, 12288) DSR(af21, aAddr1, 12288) \
    DSR(af30, aAddr0, 14336) DSR(af31, aAddr1, 14336) }
#define RD_A_B1Q0 { DSR(af00, aAddr0, 32768) DSR(af01, aAddr1, 32768) \
    DSR(af10, aAddr0, 34816) DSR(af11, aAddr1, 34816) \
    DSR(af20, aAddr0, 36864) DSR(af21, aAddr1, 36864) \
    DSR(af30, aAddr0, 38912) DSR(af31, aAddr1, 38912) }
#define RD_A_B1Q1 { DSR(af00, aAddr0, 40960) DSR(af01, aAddr1, 40960) \
    DSR(af10, aAddr0, 43008) DSR(af11, aAddr1, 43008) \
    DSR(af20, aAddr0, 45056) DSR(af21, aAddr1, 45056) \
    DSR(af30, aAddr0, 47104) DSR(af31, aAddr1, 47104) }
  // B-frag reads: bf(ni,ks); offsets buf*32768 + qn*4096 + ni*2048
#define RD_B_B0Q0 { DSR(bf00, bAddr0, 0) DSR(bf01, bAddr1, 0) \
    DSR(bf10, bAddr0, 2048) DSR(bf11, bAddr1, 2048) }
#define RD_B_B0Q1 { DSR(bf00, bAddr0, 4096) DSR(bf01, bAddr1, 4096) \
    DSR(bf10, bAddr0, 6144) DSR(bf11, bAddr1, 6144) }
#define RD_B_B1Q0 { DSR(bf00, bAddr0, 32768) DSR(bf01, bAddr1, 32768) \
    DSR(bf10, bAddr0, 34816) DSR(bf11, bAddr1, 34816) }
#define RD_B_B1Q1 { DSR(bf00, bAddr0, 36864) DSR(bf01, bAddr1, 36864) \
    DSR(bf10, bAddr0, 38912) DSR(bf11, bAddr1, 38912) }

#define MM(FI, KS, NI, QM, QN) \
  acc[(QM)*4+(FI)][(QN)*2+(NI)] = __builtin_amdgcn_mfma_f32_16x16x32_bf16( \
      af##FI##KS, bf##NI##KS, acc[(QM)*4+(FI)][(QN)*2+(NI)], 0, 0, 0);
#define MFMA16(QM, QN) { __builtin_amdgcn_s_setprio(1); \
    MM(0,0,0,QM,QN) MM(1,0,0,QM,QN) MM(2,0,0,QM,QN) MM(3,0,0,QM,QN) \
    MM(0,0,1,QM,QN) MM(1,0,1,QM,QN) MM(2,0,1,QM,QN) MM(3,0,1,QM,QN) \
    MM(0,1,0,QM,QN) MM(1,1,0,QM,QN) MM(2,1,0,QM,QN) MM(3,1,0,QM,QN) \
    MM(0,1,1,QM,QN) MM(1,1,1,QM,QN) MM(2,1,1,QM,QN) MM(3,1,1,QM,QN) \
    __builtin_amdgcn_s_setprio(0); }

#define STG_AH0(tl, NB) { gload_lds16(As00 + (size_t)(tl) * 64, &LA[NB][0][0] + t5 * 8); \
                          gload_lds16(As01 + (size_t)(tl) * 64, &LA[NB][0][0] + t5 * 8 + 4096); }
#define STG_AH1(tl, NB) { gload_lds16(As10 + (size_t)(tl) * 64, &LA[NB][1][0] + t5 * 8); \
                          gload_lds16(As11 + (size_t)(tl) * 64, &LA[NB][1][0] + t5 * 8 + 4096); }
#define STG_BH0(tl, NB) { gload_lds16(Bs00 + (size_t)(tl) * 64, &LB[NB][0][0] + t5 * 8); \
                          gload_lds16(Bs01 + (size_t)(tl) * 64, &LB[NB][0][0] + t5 * 8 + 4096); }
#define STG_BH1(tl, NB) { gload_lds16(Bs10 + (size_t)(tl) * 64, &LB[NB][1][0] + t5 * 8); \
                          gload_lds16(Bs11 + (size_t)(tl) * 64, &LB[NB][1][0] + t5 * 8 + 4096); }

#define GROUP(RDA0, RDA1, RDB0, RDB1, NB, j) { \
    const int tl = (j) + 1; const bool st = (j) < NT2 - 1; \
    RDA0 RDB0 \
    if (st) STG_AH0(tl, NB) \
    BAR(); LGKM0(); MFMA16(0, 0) BAR(); \
    RDB1 \
    if (st) STG_AH1(tl, NB) \
    BAR(); LGKM0(); MFMA16(0, 1) BAR(); \
    RDA1 \
    if (st) STG_BH0(tl, NB) \
    BAR(); LGKM0(); MFMA16(1, 1) BAR(); \
    RDB0 \
    if (st) STG_BH1(tl, NB) \
    BAR(); LGKM0(); MFMA16(1, 0) \
    VMCNT(0); BAR(); }

  // prologue: stage tile 0 into buf 0
  STG_AH0(0, 0) STG_AH1(0, 0) STG_BH0(0, 0) STG_BH1(0, 0)
  VMCNT(0);
  BAR();

  for (int j2 = 0; j2 < NT2; j2 += 2) {
    GROUP(RD_A_B0Q0, RD_A_B0Q1, RD_B_B0Q0, RD_B_B0Q1, 1, j2)
    GROUP(RD_A_B1Q0, RD_A_B1Q1, RD_B_B1Q0, RD_B_B1Q1, 0, j2 + 1)
  }

  // epilogue: z[row][col], C layout col=lane&15, row=(lane>>4)*4+reg
  #pragma unroll
  for (int mi = 0; mi < 8; ++mi) {
    #pragma unroll
    for (int ni = 0; ni < 4; ++ni) {
      #pragma unroll
      for (int rr = 0; rr < 4; ++rr) {
        const int row = am0 + wm * 128 + mi * 16 + kq * 4 + rr;
        const int col = bn0 + wn * 64 + ni * 16 + frow;
        z[(size_t)row * 2560 + col] = f2bf(acc[mi][ni][rr]);
      }
    }
  }
}

// ---- gate epilogue: read z (bf16), c_prev, s (from A), bg -> h,c ----
__global__ __launch_bounds__(256) void gate_kernel(
    const u16* __restrict__ z, const u16* __restrict__ A,
    const float* __restrict__ c_prev, const float* __restrict__ bg,
    float* __restrict__ out) {
  const int t = threadIdx.x;
  const int r = blockIdx.x * 4 + (t >> 6);
  const int h0 = (t & 63) * 8;
  const u16* zr = z + (size_t)r * 2560;

  float zg[5][8];
  #pragma unroll
  for (int g = 0; g < 5; ++g) {
    bf16x8 v = *(const bf16x8*)(zr + g * 512 + h0);
    #pragma unroll
    for (int j = 0; j < 8; ++j)
      zg[g][j] = bf2f((u16)v[j]) + bg[g * 512 + h0 + j];
  }
  bf16x8 sv = *(const bf16x8*)(A + (size_t)r * KG + 1024 + h0);
  float4 cp0 = *(const float4*)(c_prev + (size_t)r * 512 + h0);
  float4 cp1 = *(const float4*)(c_prev + (size_t)r * 512 + h0 + 4);

  float hv[8], cv[8];
  #pragma unroll
  for (int j = 0; j < 8; ++j) {
    const float cp = (j < 4) ? ((const float*)&cp0)[j] : ((const float*)&cp1)[j - 4];
    const float fg = sigm(zg[0][j]);
    const float ig = sigm(zg[1][j]);
    const float Tg = sigm(zg[2][j]);
    const float ze = tanh_(zg[3][j]);
    const float og = sigm(zg[4][j]);
    const float st = bf2f((u16)sv[j]);
    const float c = fg * cp + ig * ze + Tg * st;
    hv[j] = og * tanh_(c);
    cv[j] = c;
  }
  float* oh = out + (size_t)r * 512 + h0;
  float* oc = out + (size_t)Bsz * Hsz + (size_t)r * 512 + h0;
  *(float4*)(oh) = make_float4(hv[0], hv[1], hv[2], hv[3]);
  *(float4*)(oh + 4) = make_float4(hv[4], hv[5], hv[6], hv[7]);
  *(float4*)(oc) = make_float4(cv[0], cv[1], cv[2], cv[3]);
  *(float4*)(oc + 4) = make_float4(cv[4], cv[5], cv[6], cv[7]);
}

extern "C" void kernel_launch(void* const* d_in, const int* in_sizes, int n_in,
                              void* d_out, int out_size, void* d_ws, size_t ws_size,
                              hipStream_t stream) {
  const float* x_t    = (const float*)d_in[0];
  const float* delta  = (const float*)d_in[1];
  const float* h_prev = (const float*)d_in[2];
  const float* c_prev = (const float*)d_in[3];
  const float* Ws     = (const float*)d_in[4];
  const float* bs     = (const float*)d_in[5];
  const float* Wg     = (const float*)d_in[6];
  const float* bg     = (const float*)d_in[7];
  float* out = (float*)d_out;

  char* wsb = (char*)d_ws;
  u16* A   = (u16*)(wsb);                          // [16384][1536] bf16 = 50,331,648 B
  u16* Wst = (u16*)(wsb + (size_t)50331648);       // [512][1024]  bf16 =  1,048,576 B
  u16* Wgt = (u16*)(wsb + (size_t)51380224);       // [2560][1536] bf16 =  7,864,320 B
  u16* zbuf = (u16*)(wsb + (size_t)59244544);      // [16384][2560] bf16 = 83,886,080 B

  prep_A_kernel<<<dim3(16384), dim3(256), 0, stream>>>(h_prev, x_t, A);
  transpose_cast_kernel<<<dim3(16, 32), dim3(32, 8), 0, stream>>>(Ws, Wst, 1024, 512);
  transpose_cast_kernel<<<dim3(80, 48), dim3(32, 8), 0, stream>>>(Wg, Wgt, 1536, 2560);
  gemm1_kernel<<<dim3(4, 128), dim3(256), 0, stream>>>(A, Wst, Ws, bs, delta, A);
  gemm2_t<<<dim3(640), dim3(512), 0, stream>>>(A, Wgt, zbuf);
  gate_kernel<<<dim3(4096), dim3(256), 0, stream>>>(zbuf, A, c_prev, bg, out);
}